// Round 5
// baseline (255.439 us; speedup 1.0000x reference)
//
#include <hip/hip_runtime.h>

typedef unsigned short u16t;
typedef short short8 __attribute__((ext_vector_type(8)));
typedef float f32x4 __attribute__((ext_vector_type(4)));

__device__ __forceinline__ u16t f2bf_rne(float f) {
  unsigned u = __builtin_bit_cast(unsigned, f);
  u += 0x7FFFu + ((u >> 16) & 1u);
  return (u16t)(u >> 16);
}
// pack two fp32 -> bf16 pair (round-half-up)
__device__ __forceinline__ unsigned pk2(float a, float b) {
  unsigned ua = __builtin_bit_cast(unsigned, a) + 0x8000u;
  unsigned ub = __builtin_bit_cast(unsigned, b) + 0x8000u;
  return (ua >> 16) | (ub & 0xFFFF0000u);
}
union S8U { short8 s; unsigned w[4]; };
__device__ __forceinline__ short8 pack8f(float4 a, float4 b) {
  S8U u;
  u.w[0] = pk2(a.x, a.y); u.w[1] = pk2(a.z, a.w);
  u.w[2] = pk2(b.x, b.y); u.w[3] = pk2(b.z, b.w);
  return u.s;
}

// d_ws byte offsets
#define WS_WB 0        // W1 B-frags (s1-folded) [p][nt][half][lane] 16B = 32768 B
#define WS_BS 32768    // sin-col frags compact [p][nt][l15] 8B        = 2048 B
#define WS_FF 34816    // {b1, w20*sq2*s2, w21*sq2*s2, 0} [p][nt][l15] = 4096 B
#define WS_BC 38912    // W2 c-col frags compact (s2-folded) 32x16B    = 512 B

#define S1C   0.121267812518166f     // 1/sqrt(68)
#define S2C   0.0721687836487032f    // 1/sqrt(192)
#define SQ2S2 0.102062072615966f     // sqrt(2)/sqrt(192)

// ---------------- prep: convert + permute + scale weights into d_ws -------
__global__ void prep_kernel(const float* __restrict__ Wx1, const float* __restrict__ bx1,
                            const float* __restrict__ Wx2,
                            const float* __restrict__ Wy1, const float* __restrict__ by1,
                            const float* __restrict__ Wy2,
                            char* __restrict__ ws)
{
  const int tid = threadIdx.x;          // 1024 threads: (p, nt, lane)
  const int p = tid >> 9, nt = (tid >> 6) & 7, lane = tid & 63;
  const int l15 = lane & 15, quad = lane >> 4;
  const float* W1 = p ? Wy1 : Wx1;
  const float* B1 = p ? by1 : bx1;
  const float* W2 = p ? Wy2 : Wx2;
  const int n = nt * 16 + l15;
  const float* rp = W1 + n * 68;
  short8 bb0, bb1;
  #pragma unroll
  for (int j = 0; j < 8; ++j) {
    bb0[j] = (short)f2bf_rne(rp[4  + quad * 8 + j] * S1C);  // K-perm: k<64 -> col 4+k
    bb1[j] = (short)f2bf_rne(rp[36 + quad * 8 + j] * S1C);
  }
  short8* wb = (short8*)(ws + WS_WB);
  wb[((p * 8 + nt) * 2 + 0) * 64 + lane] = bb0;
  wb[((p * 8 + nt) * 2 + 1) * 64 + lane] = bb1;
  if (quad == 0) {
    ushort4 b4;
    b4.x = f2bf_rne(rp[0] * S1C); b4.y = f2bf_rne(rp[1] * S1C);
    b4.z = f2bf_rne(rp[2] * S1C); b4.w = f2bf_rne(rp[3] * S1C);
    *(ushort4*)(ws + WS_BS + ((p * 8 + nt) * 16 + l15) * 8) = b4;
    float4 ff;
    ff.x = B1[n]; ff.y = W2[n] * SQ2S2; ff.z = W2[192 + n] * SQ2S2; ff.w = 0.f;
    *(float4*)(ws + WS_FF + ((p * 8 + nt) * 16 + l15) * 16) = ff;
  }
  if (tid < 32) {   // W2 c-cols as compact B-frags: (p,h,l2,q) = tid bits
    const int p2 = tid >> 4, h = (tid >> 3) & 1, l2 = (tid >> 2) & 1, q = tid & 3;
    const float* W2b = p2 ? Wy2 : Wx2;
    const float* src = W2b + l2 * 192 + 128 + h * 32 + q * 8;
    short8 bc;
    #pragma unroll
    for (int j = 0; j < 8; ++j) bc[j] = (short)f2bf_rne(src[j] * S2C);
    *(short8*)(ws + WS_BC + tid * 16) = bc;
  }
}

// ---------------- main: zero LDS, 64 rows/wave ----------------------------
__global__ __launch_bounds__(256, 3)
void icb_main(const float* __restrict__ g_coords, const float* __restrict__ g_c,
              const float* __restrict__ g_bx2, const float* __restrict__ g_by2,
              const char* __restrict__ ws, float* __restrict__ g_out)
{
  const int tid  = threadIdx.x;
  const int lane = tid & 63, wave = tid >> 6;
  const int l15  = lane & 15, quad = lane >> 4;
  const int wbase = blockIdx.x * 256 + wave * 64;   // 4 m-tiles of 16 rows

  const short8* wb = (const short8*)(ws + WS_WB);

  // A-frags for c, straight from global (K-perm: k 0..63 = c cols)
  short8 aC0[4], aC1[4];
  float xold[4], yold[4];
  #pragma unroll
  for (int mt = 0; mt < 4; ++mt) {
    const int r = wbase + mt * 16 + l15;
    const float4* cr = (const float4*)(g_c + (size_t)r * 64);
    aC0[mt] = pack8f(cr[quad * 2],     cr[quad * 2 + 1]);
    aC1[mt] = pack8f(cr[8 + quad * 2], cr[8 + quad * 2 + 1]);
    float2 pxy = ((const float2*)g_coords)[r];
    xold[mt] = pxy.x; yold[mt] = pxy.y;
  }

  float vin[4], xnew[4], ynew[4], xls[4], yls[4];
  #pragma unroll
  for (int mt = 0; mt < 4; ++mt) vin[mt] = xold[mt];

  #pragma unroll 1
  for (int path = 0; path < 2; ++path) {
    const int pb = path * 8;
    const float* b2 = path ? g_by2 : g_bx2;
    const float b20 = b2[0], b21 = b2[1];

    // c-part B-frags early (consumed after nt loop)
    short8 bc0 = (short8)0, bc1 = (short8)0;
    if (l15 < 2) {
      bc0 = *(const short8*)(ws + WS_BC + (path * 16 +     l15 * 4 + quad) * 16);
      bc1 = *(const short8*)(ws + WS_BC + (path * 16 + 8 + l15 * 4 + quad) * 16);
    }

    // sinusoidal A-frags: k 64..67 = [sin a, sin 2a, cos a, cos 2a] (quad 0)
    short8 aS[4];
    #pragma unroll
    for (int mt = 0; mt < 4; ++mt) {
      short8 f = (short8)0;
      if (quad == 0) {
        float a  = vin[mt] * 0.1f;
        float sa = __sinf(a), ca = __cosf(a);
        float s2a = 2.0f * sa * ca;
        float c2a = fmaf(-2.0f * sa, sa, 1.0f);
        f[0] = (short)f2bf_rne(sa); f[1] = (short)f2bf_rne(s2a);
        f[2] = (short)f2bf_rne(ca); f[3] = (short)f2bf_rne(c2a);
      }
      aS[mt] = f;
    }

    float hp[4][4][2];
    #pragma unroll
    for (int mt = 0; mt < 4; ++mt)
      #pragma unroll
      for (int j = 0; j < 4; ++j) { hp[mt][j][0] = 0.f; hp[mt][j][1] = 0.f; }

    #pragma unroll 2
    for (int nt = 0; nt < 8; ++nt) {
      short8 bb0 = wb[((pb + nt) * 2 + 0) * 64 + lane];
      short8 bb1 = wb[((pb + nt) * 2 + 1) * 64 + lane];
      short8 bs = (short8)0;
      if (quad == 0) {
        uint2 rw = *(const uint2*)(ws + WS_BS + ((pb + nt) * 16 + l15) * 8);
        S8U u; u.w[0] = rw.x; u.w[1] = rw.y; u.w[2] = 0; u.w[3] = 0;
        bs = u.s;
      }
      float4 ff = *(const float4*)(ws + WS_FF + ((pb + nt) * 16 + l15) * 16);
      #pragma unroll
      for (int mt = 0; mt < 4; ++mt) {
        f32x4 acc = {ff.x, ff.x, ff.x, ff.x};   // C-init = b1 (s1 folded into B)
        acc = __builtin_amdgcn_mfma_f32_16x16x32_bf16(aC0[mt], bb0, acc, 0, 0, 0);
        acc = __builtin_amdgcn_mfma_f32_16x16x32_bf16(aC1[mt], bb1, acc, 0, 0, 0);
        acc = __builtin_amdgcn_mfma_f32_16x16x32_bf16(aS[mt],  bs,  acc, 0, 0, 0);
        #pragma unroll
        for (int j = 0; j < 4; ++j) {
          float v = acc[j];
          float h = fmaxf(v, 0.2f * v);         // leaky (sqrt2*s2 folded into ff.y/z)
          hp[mt][j][0] = fmaf(h, ff.y, hp[mt][j][0]);
          hp[mt][j][1] = fmaf(h, ff.z, hp[mt][j][1]);
        }
      }
    }

    // layer-2 c-part (s2 folded into bc; b2 via C-init) and fold into hp
    const float cinit = (l15 == 0) ? b20 : ((l15 == 1) ? b21 : 0.f);
    #pragma unroll
    for (int mt = 0; mt < 4; ++mt) {
      f32x4 a = {cinit, cinit, cinit, cinit};
      a = __builtin_amdgcn_mfma_f32_16x16x32_bf16(aC0[mt], bc0, a, 0, 0, 0);
      a = __builtin_amdgcn_mfma_f32_16x16x32_bf16(aC1[mt], bc1, a, 0, 0, 0);
      #pragma unroll
      for (int j = 0; j < 4; ++j) {
        hp[mt][j][0] += (l15 == 0) ? a[j] : 0.f;
        hp[mt][j][1] += (l15 == 1) ? a[j] : 0.f;
      }
    }

    // paired butterfly over the 16-lane quad groups: o0 result in l15<8, o1 in l15>=8
    const int jm   = l15 & 3;
    const int srcA = ((l15 >> 2) << 4) | jm;   // source lane self-selects mm[jm]
    const int srcB = srcA | 8;
    #pragma unroll
    for (int mt = 0; mt < 4; ++mt) {
      float mm[4];
      #pragma unroll
      for (int j = 0; j < 4; ++j) {
        float a = hp[mt][j][0], b = hp[mt][j][1];
        a += __shfl_xor(a, 8);
        b += __shfl_xor(b, 8);
        float m = (l15 & 8) ? b : a;
        m += __shfl_xor(m, 1);
        m += __shfl_xor(m, 2);
        m += __shfl_xor(m, 4);
        mm[j] = m;
      }
      float msel = (jm & 2) ? ((jm & 1) ? mm[3] : mm[2])
                            : ((jm & 1) ? mm[1] : mm[0]);
      float lsraw = __shfl(msel, srcA);
      float brow  = __shfl(msel, srcB);

      float ls = fminf(fmaxf(lsraw, -5.f), 5.f);
      float e  = __expf(ls);
      if (path == 0) {
        yls[mt]  = ls;
        ynew[mt] = fmaf(yold[mt], e, brow);
        vin[mt]  = ynew[mt];          // y-path sinusoidals use updated y
      } else {
        xls[mt]  = ls;
        xnew[mt] = fmaf(xold[mt], e, brow);
      }
    }
  }

  // outputs: warped (x,y) then log_jac, fp32
  if (lane < 16) {
    #pragma unroll
    for (int mt = 0; mt < 4; ++mt) {
      int R = wbase + mt * 16 + lane;
      float2 pw; pw.x = xnew[mt]; pw.y = ynew[mt];
      reinterpret_cast<float2*>(g_out)[R] = pw;
      g_out[1048576 + R] = xls[mt] + yls[mt];
    }
  }
}

extern "C" void kernel_launch(void* const* d_in, const int* in_sizes, int n_in,
                              void* d_out, int out_size, void* d_ws, size_t ws_size,
                              hipStream_t stream) {
  (void)in_sizes; (void)n_in; (void)out_size; (void)ws_size;
  prep_kernel<<<1, 1024, 0, stream>>>(
      (const float*)d_in[2], (const float*)d_in[3], (const float*)d_in[4],
      (const float*)d_in[6], (const float*)d_in[7], (const float*)d_in[8],
      (char*)d_ws);
  icb_main<<<2048, 256, 0, stream>>>(
      (const float*)d_in[0], (const float*)d_in[1],
      (const float*)d_in[5], (const float*)d_in[9],
      (const char*)d_ws, (float*)d_out);
}

// Round 6
// 243.148 us; speedup vs baseline: 1.0505x; 1.0505x over previous
//
#include <hip/hip_runtime.h>

typedef unsigned short u16t;
typedef short short8 __attribute__((ext_vector_type(8)));
typedef float f32x4 __attribute__((ext_vector_type(4)));
typedef float f32x2 __attribute__((ext_vector_type(2)));

__device__ __forceinline__ u16t f2bf_rne(float f) {
  unsigned u = __builtin_bit_cast(unsigned, f);
  u += 0x7FFFu + ((u >> 16) & 1u);
  return (u16t)(u >> 16);
}
// pack two fp32 -> bf16 pair (round-half-up)
__device__ __forceinline__ unsigned pk2(float a, float b) {
  unsigned ua = __builtin_bit_cast(unsigned, a) + 0x8000u;
  unsigned ub = __builtin_bit_cast(unsigned, b) + 0x8000u;
  return (ua >> 16) | (ub & 0xFFFF0000u);
}
union S8U { short8 s; unsigned w[4]; };
__device__ __forceinline__ short8 pack8f(float4 a, float4 b) {
  S8U u;
  u.w[0] = pk2(a.x, a.y); u.w[1] = pk2(a.z, a.w);
  u.w[2] = pk2(b.x, b.y); u.w[3] = pk2(b.z, b.w);
  return u.s;
}

// d_ws byte offsets
#define WS_WB 0        // W1 B-frags (s1-folded) [p][nt][half][lane] 16B = 32768 B
#define WS_BS 32768    // sin-col frags compact [p][nt][l15] 8B        = 2048 B
#define WS_FF 34816    // {b1, w20*sq2*s2, w21*sq2*s2, 0} [p][nt][l15] = 4096 B
#define WS_BC 38912    // W2 c-col frags compact (s2-folded) 32x16B    = 512 B

#define S1C   0.121267812518166f     // 1/sqrt(68)
#define S2C   0.0721687836487032f    // 1/sqrt(192)
#define SQ2S2 0.102062072615966f     // sqrt(2)/sqrt(192)

// ---------------- prep: convert + permute + scale weights into d_ws -------
__global__ void prep_kernel(const float* __restrict__ Wx1, const float* __restrict__ bx1,
                            const float* __restrict__ Wx2,
                            const float* __restrict__ Wy1, const float* __restrict__ by1,
                            const float* __restrict__ Wy2,
                            char* __restrict__ ws)
{
  const int tid = threadIdx.x;          // 1024 threads: (p, nt, lane)
  const int p = tid >> 9, nt = (tid >> 6) & 7, lane = tid & 63;
  const int l15 = lane & 15, quad = lane >> 4;
  const float* W1 = p ? Wy1 : Wx1;
  const float* B1 = p ? by1 : bx1;
  const float* W2 = p ? Wy2 : Wx2;
  const int n = nt * 16 + l15;
  const float* rp = W1 + n * 68;
  short8 bb0, bb1;
  #pragma unroll
  for (int j = 0; j < 8; ++j) {
    bb0[j] = (short)f2bf_rne(rp[4  + quad * 8 + j] * S1C);  // K-perm: k<64 -> col 4+k
    bb1[j] = (short)f2bf_rne(rp[36 + quad * 8 + j] * S1C);
  }
  short8* wb = (short8*)(ws + WS_WB);
  wb[((p * 8 + nt) * 2 + 0) * 64 + lane] = bb0;
  wb[((p * 8 + nt) * 2 + 1) * 64 + lane] = bb1;
  if (quad == 0) {
    ushort4 b4;
    b4.x = f2bf_rne(rp[0] * S1C); b4.y = f2bf_rne(rp[1] * S1C);
    b4.z = f2bf_rne(rp[2] * S1C); b4.w = f2bf_rne(rp[3] * S1C);
    *(ushort4*)(ws + WS_BS + ((p * 8 + nt) * 16 + l15) * 8) = b4;
    float4 ff;
    ff.x = B1[n]; ff.y = W2[n] * SQ2S2; ff.z = W2[192 + n] * SQ2S2; ff.w = 0.f;
    *(float4*)(ws + WS_FF + ((p * 8 + nt) * 16 + l15) * 16) = ff;
  }
  if (tid < 32) {   // W2 c-cols as compact B-frags: (p,h,l2,q) = tid bits
    const int p2 = tid >> 4, h = (tid >> 3) & 1, l2 = (tid >> 2) & 1, q = tid & 3;
    const float* W2b = p2 ? Wy2 : Wx2;
    const float* src = W2b + l2 * 192 + 128 + h * 32 + q * 8;
    short8 bc;
    #pragma unroll
    for (int j = 0; j < 8; ++j) bc[j] = (short)f2bf_rne(src[j] * S2C);
    *(short8*)(ws + WS_BC + tid * 16) = bc;
  }
}

// ---------------- main: zero LDS, 64 rows/wave, pinned 3 waves/EU ---------
__global__ __launch_bounds__(256) __attribute__((amdgpu_waves_per_eu(3, 4)))
void icb_main(const float* __restrict__ g_coords, const float* __restrict__ g_c,
              const float* __restrict__ g_bx2, const float* __restrict__ g_by2,
              const char* __restrict__ ws, float* __restrict__ g_out)
{
  const int tid  = threadIdx.x;
  const int lane = tid & 63, wave = tid >> 6;
  const int l15  = lane & 15, quad = lane >> 4;
  const int wbase = blockIdx.x * 256 + wave * 64;   // 4 m-tiles of 16 rows

  const short8* wb = (const short8*)(ws + WS_WB);

  // A-frags for c, straight from global (K-perm: k 0..63 = c cols)
  short8 aC0[4], aC1[4];
  float xold[4], yold[4];
  #pragma unroll
  for (int mt = 0; mt < 4; ++mt) {
    const int r = wbase + mt * 16 + l15;
    const float4* cr = (const float4*)(g_c + (size_t)r * 64);
    aC0[mt] = pack8f(cr[quad * 2],     cr[quad * 2 + 1]);
    aC1[mt] = pack8f(cr[8 + quad * 2], cr[8 + quad * 2 + 1]);
    float2 pxy = ((const float2*)g_coords)[r];
    xold[mt] = pxy.x; yold[mt] = pxy.y;
  }

  float vin[4], xnew[4], ynew[4], xls[4], yls[4];
  #pragma unroll
  for (int mt = 0; mt < 4; ++mt) vin[mt] = xold[mt];

  #pragma unroll 1
  for (int path = 0; path < 2; ++path) {
    const int pb = path * 8;
    const float* b2 = path ? g_by2 : g_bx2;
    const float b20 = b2[0], b21 = b2[1];

    // sinusoidal A-frags: k 64..67 = [sin a, sin 2a, cos a, cos 2a] (quad 0)
    short8 aS[4];
    #pragma unroll
    for (int mt = 0; mt < 4; ++mt) {
      short8 f = (short8)0;
      if (quad == 0) {
        float a  = vin[mt] * 0.1f;
        float sa = __sinf(a), ca = __cosf(a);
        float s2a = 2.0f * sa * ca;
        float c2a = fmaf(-2.0f * sa, sa, 1.0f);
        f[0] = (short)f2bf_rne(sa); f[1] = (short)f2bf_rne(s2a);
        f[2] = (short)f2bf_rne(ca); f[3] = (short)f2bf_rne(c2a);
      }
      aS[mt] = f;
    }

    f32x2 hp[4][4];   // [mt][j] -> (o0, o1), packed-fp32 accumulate
    #pragma unroll
    for (int mt = 0; mt < 4; ++mt)
      #pragma unroll
      for (int j = 0; j < 4; ++j) hp[mt][j] = (f32x2){0.f, 0.f};

    #pragma unroll 2
    for (int nt = 0; nt < 8; ++nt) {
      short8 bb0 = wb[((pb + nt) * 2 + 0) * 64 + lane];
      short8 bb1 = wb[((pb + nt) * 2 + 1) * 64 + lane];
      short8 bs = (short8)0;
      if (quad == 0) {
        uint2 rw = *(const uint2*)(ws + WS_BS + ((pb + nt) * 16 + l15) * 8);
        S8U u; u.w[0] = rw.x; u.w[1] = rw.y; u.w[2] = 0; u.w[3] = 0;
        bs = u.s;
      }
      float4 ff = *(const float4*)(ws + WS_FF + ((pb + nt) * 16 + l15) * 16);
      const f32x2 wv = {ff.y, ff.z};
      #pragma unroll
      for (int mt = 0; mt < 4; ++mt) {
        f32x4 acc = {ff.x, ff.x, ff.x, ff.x};   // C-init = b1 (s1 folded into B)
        acc = __builtin_amdgcn_mfma_f32_16x16x32_bf16(aC0[mt], bb0, acc, 0, 0, 0);
        acc = __builtin_amdgcn_mfma_f32_16x16x32_bf16(aC1[mt], bb1, acc, 0, 0, 0);
        acc = __builtin_amdgcn_mfma_f32_16x16x32_bf16(aS[mt],  bs,  acc, 0, 0, 0);
        #pragma unroll
        for (int j = 0; j < 4; ++j) {
          float v = acc[j];
          float h = fmaxf(v, 0.2f * v);         // leaky (sqrt2*s2 folded into wv)
          f32x2 hv = {h, h};
          hp[mt][j] += hv * wv;                  // v_pk_fma_f32
        }
      }
    }

    // layer-2 c-part (s2 folded into bc; b2 via C-init) and fold into hp
    short8 bc0 = (short8)0, bc1 = (short8)0;
    if (l15 < 2) {
      bc0 = *(const short8*)(ws + WS_BC + (path * 16 +     l15 * 4 + quad) * 16);
      bc1 = *(const short8*)(ws + WS_BC + (path * 16 + 8 + l15 * 4 + quad) * 16);
    }
    const float cinit = (l15 == 0) ? b20 : ((l15 == 1) ? b21 : 0.f);
    #pragma unroll
    for (int mt = 0; mt < 4; ++mt) {
      f32x4 a = {cinit, cinit, cinit, cinit};
      a = __builtin_amdgcn_mfma_f32_16x16x32_bf16(aC0[mt], bc0, a, 0, 0, 0);
      a = __builtin_amdgcn_mfma_f32_16x16x32_bf16(aC1[mt], bc1, a, 0, 0, 0);
      #pragma unroll
      for (int j = 0; j < 4; ++j) {
        hp[mt][j].x += (l15 == 0) ? a[j] : 0.f;
        hp[mt][j].y += (l15 == 1) ? a[j] : 0.f;
      }
    }

    // paired butterfly over the 16-lane quad groups: o0 result in l15<8, o1 in l15>=8
    const int jm   = l15 & 3;
    const int srcA = ((l15 >> 2) << 4) | jm;   // source lane self-selects mm[jm]
    const int srcB = srcA | 8;
    #pragma unroll
    for (int mt = 0; mt < 4; ++mt) {
      float mm[4];
      #pragma unroll
      for (int j = 0; j < 4; ++j) {
        float a = hp[mt][j].x, b = hp[mt][j].y;
        a += __shfl_xor(a, 8);
        b += __shfl_xor(b, 8);
        float m = (l15 & 8) ? b : a;
        m += __shfl_xor(m, 1);
        m += __shfl_xor(m, 2);
        m += __shfl_xor(m, 4);
        mm[j] = m;
      }
      float msel = (jm & 2) ? ((jm & 1) ? mm[3] : mm[2])
                            : ((jm & 1) ? mm[1] : mm[0]);
      float lsraw = __shfl(msel, srcA);
      float brow  = __shfl(msel, srcB);

      float ls = fminf(fmaxf(lsraw, -5.f), 5.f);
      float e  = __expf(ls);
      if (path == 0) {
        yls[mt]  = ls;
        ynew[mt] = fmaf(yold[mt], e, brow);
        vin[mt]  = ynew[mt];          // y-path sinusoidals use updated y
      } else {
        xls[mt]  = ls;
        xnew[mt] = fmaf(xold[mt], e, brow);
      }
    }
  }

  // outputs: warped (x,y) then log_jac, fp32
  if (lane < 16) {
    #pragma unroll
    for (int mt = 0; mt < 4; ++mt) {
      int R = wbase + mt * 16 + lane;
      float2 pw; pw.x = xnew[mt]; pw.y = ynew[mt];
      reinterpret_cast<float2*>(g_out)[R] = pw;
      g_out[1048576 + R] = xls[mt] + yls[mt];
    }
  }
}

extern "C" void kernel_launch(void* const* d_in, const int* in_sizes, int n_in,
                              void* d_out, int out_size, void* d_ws, size_t ws_size,
                              hipStream_t stream) {
  (void)in_sizes; (void)n_in; (void)out_size; (void)ws_size;
  prep_kernel<<<1, 1024, 0, stream>>>(
      (const float*)d_in[2], (const float*)d_in[3], (const float*)d_in[4],
      (const float*)d_in[6], (const float*)d_in[7], (const float*)d_in[8],
      (char*)d_ws);
  icb_main<<<2048, 256, 0, stream>>>(
      (const float*)d_in[0], (const float*)d_in[1],
      (const float*)d_in[5], (const float*)d_in[9],
      (const char*)d_ws, (float*)d_out);
}